// Round 1
// baseline (151.469 us; speedup 1.0000x reference)
//
#include <hip/hip_runtime.h>

#define B_  8
#define TQ  128
#define TV  128
#define DIM 512
#define UU  1024

// ---------------------------------------------------------------------------
// Kernel 1: dual fp32 tiled GEMM.  z=0: WQ = Q@W1 ; z=1: WK = V@W2
// M=1024 (B*T), N=1024 (U), K=512 (D). 64x64 tile / block, 4x4 per thread.
// ---------------------------------------------------------------------------
__global__ __launch_bounds__(256) void k_proj(
    const float* __restrict__ Q, const float* __restrict__ Vv,
    const float* __restrict__ W1, const float* __restrict__ W2,
    float* __restrict__ WQ, float* __restrict__ WK)
{
    const int N = UU, K = DIM;
    const float* A = blockIdx.z ? Vv : Q;
    const float* W = blockIdx.z ? W2 : W1;
    float*       C = blockIdx.z ? WK : WQ;

    __shared__ float As[32][64];   // [k][m] (transposed on store)
    __shared__ float Bs[32][68];   // [k][n] padded to dodge k-stride conflicts

    const int tid  = threadIdx.x;
    const int tx   = tid & 15;     // n quad
    const int ty   = tid >> 4;     // m quad
    const int row0 = blockIdx.y * 64;
    const int col0 = blockIdx.x * 64;

    // staging assignments
    const int a_kq = tid & 7;      // float4 index along k (0..7 covers 32 k)
    const int a_m  = tid >> 3;     // 0..31 (two halves)
    const int b_n4 = (tid & 15) * 4;
    const int b_k  = tid >> 4;     // 0..15 (two halves)

    float acc[4][4] = {};

    for (int kt = 0; kt < K; kt += 32) {
        #pragma unroll
        for (int h = 0; h < 2; ++h) {
            int m = a_m + h * 32;
            float4 av = *(const float4*)&A[(row0 + m) * K + kt + a_kq * 4];
            As[a_kq * 4 + 0][m] = av.x;
            As[a_kq * 4 + 1][m] = av.y;
            As[a_kq * 4 + 2][m] = av.z;
            As[a_kq * 4 + 3][m] = av.w;
        }
        #pragma unroll
        for (int h = 0; h < 2; ++h) {
            int k = b_k + h * 16;
            *(float4*)&Bs[k][b_n4] = *(const float4*)&W[(kt + k) * N + col0 + b_n4];
        }
        __syncthreads();
        #pragma unroll
        for (int k = 0; k < 32; ++k) {
            float4 a = *(const float4*)&As[k][ty * 4];
            float4 b = *(const float4*)&Bs[k][tx * 4];
            float af[4] = {a.x, a.y, a.z, a.w};
            float bf[4] = {b.x, b.y, b.z, b.w};
            #pragma unroll
            for (int i = 0; i < 4; ++i)
                #pragma unroll
                for (int j = 0; j < 4; ++j)
                    acc[i][j] = fmaf(af[i], bf[j], acc[i][j]);
        }
        __syncthreads();
    }
    #pragma unroll
    for (int i = 0; i < 4; ++i) {
        float4 o = {acc[i][0], acc[i][1], acc[i][2], acc[i][3]};
        *(float4*)&C[(row0 + ty * 4 + i) * N + col0 + tx * 4] = o;
    }
}

// ---------------------------------------------------------------------------
// Kernel 2: scores[b,t,s] = sum_u scale[u]*tanh(wq[b,t,u]+wk[b,s,u]), masked.
// Block = 16x16 (t,s) tile for one b; u staged in chunks of 128.
// tanh(x) = 1 - 2*rcp(exp2(2x*log2e)+1)
// ---------------------------------------------------------------------------
__global__ __launch_bounds__(256) void k_scores(
    const float* __restrict__ WQ, const float* __restrict__ WK,
    const float* __restrict__ scale, const int* __restrict__ mask,
    float* __restrict__ scores)
{
    __shared__ float qs[16][132];
    __shared__ float ks[16][132];
    __shared__ float ss[128];

    const int tid = threadIdx.x;
    const int tx  = tid & 15;   // s within tile
    const int ty  = tid >> 4;   // t within tile
    const int b   = blockIdx.z;
    const int t0  = blockIdx.y * 16;
    const int s0  = blockIdx.x * 16;

    const int lr = tid >> 4;          // staging row 0..15
    const int lc = (tid & 15) * 8;    // staging col 0..120

    float acc = 0.f;
    for (int uc = 0; uc < UU; uc += 128) {
        {
            const float* srq = &WQ[(b * TQ + t0 + lr) * UU + uc + lc];
            *(float4*)&qs[lr][lc]     = *(const float4*)srq;
            *(float4*)&qs[lr][lc + 4] = *(const float4*)(srq + 4);
            const float* srk = &WK[(b * TV + s0 + lr) * UU + uc + lc];
            *(float4*)&ks[lr][lc]     = *(const float4*)srk;
            *(float4*)&ks[lr][lc + 4] = *(const float4*)(srk + 4);
        }
        if (tid < 32)
            *(float4*)&ss[tid * 4] = *(const float4*)&scale[uc + tid * 4];
        __syncthreads();
        #pragma unroll 4
        for (int u4 = 0; u4 < 32; ++u4) {
            float4 q  = *(const float4*)&qs[ty][u4 * 4];
            float4 k  = *(const float4*)&ks[tx][u4 * 4];
            float4 sc = *(const float4*)&ss[u4 * 4];
            float xq[4] = {q.x, q.y, q.z, q.w};
            float xk[4] = {k.x, k.y, k.z, k.w};
            float xs[4] = {sc.x, sc.y, sc.z, sc.w};
            #pragma unroll
            for (int j = 0; j < 4; ++j) {
                float x  = xq[j] + xk[j];
                float e  = __builtin_amdgcn_exp2f(x * 2.885390081777927f); // e^(2x)
                float r  = __builtin_amdgcn_rcpf(e + 1.0f);
                float th = fmaf(-2.0f, r, 1.0f);                          // tanh(x)
                acc = fmaf(xs[j], th, acc);
            }
        }
        __syncthreads();
    }
    const int t = t0 + ty, s = s0 + tx;
    const int mk = mask[b * TV + s];
    scores[(b * TQ + t) * TV + s] = mk ? acc : -1e9f;
}

// ---------------------------------------------------------------------------
// Kernel 3: in-place row softmax over s (row length 128). One wave per row.
// ---------------------------------------------------------------------------
__global__ __launch_bounds__(256) void k_softmax(float* __restrict__ scores)
{
    const int tid  = threadIdx.x;
    const int wave = tid >> 6;
    const int lane = tid & 63;
    const int row  = blockIdx.x * 4 + wave;
    float* p = &scores[row * TV];

    float x0 = p[lane], x1 = p[lane + 64];
    float m = fmaxf(x0, x1);
    #pragma unroll
    for (int o = 32; o > 0; o >>= 1) m = fmaxf(m, __shfl_xor(m, o, 64));
    const float L2E = 1.4426950408889634f;
    float e0 = __builtin_amdgcn_exp2f((x0 - m) * L2E);
    float e1 = __builtin_amdgcn_exp2f((x1 - m) * L2E);
    float s = e0 + e1;
    #pragma unroll
    for (int o = 32; o > 0; o >>= 1) s += __shfl_xor(s, o, 64);
    float r = __builtin_amdgcn_rcpf(s);
    p[lane]      = e0 * r;
    p[lane + 64] = e1 * r;
}

// ---------------------------------------------------------------------------
// Kernel 4: context[b,t,d] = sum_s attn[b,t,s] * value[b,s,d]
// Block: one b, 16 t's, 128 d's. attn tile transposed in LDS.
// ---------------------------------------------------------------------------
__global__ __launch_bounds__(256) void k_context(
    const float* __restrict__ attn, const float* __restrict__ Vv,
    float* __restrict__ ctx)
{
    __shared__ float at[128][20];   // [s][t_local], padded pitch (80B, 16B-aligned)

    const int tid = threadIdx.x;
    const int b   = blockIdx.z;
    const int tt  = blockIdx.y;     // t tile of 16
    const int dc  = blockIdx.x;     // d chunk of 128
    {
        int tl = tid & 15;
        int s0 = (tid >> 4) * 8;
        const float* src = &attn[(b * TQ + tt * 16 + tl) * TV + s0];
        float4 a0 = *(const float4*)src;
        float4 a1 = *(const float4*)(src + 4);
        at[s0 + 0][tl] = a0.x; at[s0 + 1][tl] = a0.y;
        at[s0 + 2][tl] = a0.z; at[s0 + 3][tl] = a0.w;
        at[s0 + 4][tl] = a1.x; at[s0 + 5][tl] = a1.y;
        at[s0 + 6][tl] = a1.z; at[s0 + 7][tl] = a1.w;
    }
    __syncthreads();

    const int d  = (tid & 127) + dc * 128;
    const int tg = tid >> 7;    // 0..1 -> which 8 t's
    float acc[8] = {};
    const float* vp = &Vv[b * TV * DIM + d];
    for (int s = 0; s < TV; ++s) {
        float v = vp[s * DIM];
        float4 a0 = *(const float4*)&at[s][tg * 8];
        float4 a1 = *(const float4*)&at[s][tg * 8 + 4];
        acc[0] = fmaf(a0.x, v, acc[0]);
        acc[1] = fmaf(a0.y, v, acc[1]);
        acc[2] = fmaf(a0.z, v, acc[2]);
        acc[3] = fmaf(a0.w, v, acc[3]);
        acc[4] = fmaf(a1.x, v, acc[4]);
        acc[5] = fmaf(a1.y, v, acc[5]);
        acc[6] = fmaf(a1.z, v, acc[6]);
        acc[7] = fmaf(a1.w, v, acc[7]);
    }
    #pragma unroll
    for (int j = 0; j < 8; ++j) {
        int t = tt * 16 + tg * 8 + j;
        ctx[(b * TQ + t) * DIM + d] = acc[j];
    }
}

// ---------------------------------------------------------------------------
extern "C" void kernel_launch(void* const* d_in, const int* in_sizes, int n_in,
                              void* d_out, int out_size, void* d_ws, size_t ws_size,
                              hipStream_t stream)
{
    const float* query = (const float*)d_in[0];
    const float* value = (const float*)d_in[1];
    const int*   mask  = (const int*)d_in[2];
    const float* W1    = (const float*)d_in[3];
    const float* W2    = (const float*)d_in[4];
    const float* scale = (const float*)d_in[5];

    float* out  = (float*)d_out;
    float* ctx  = out;                    // [B, Tq, D]   = 524288 floats
    float* attn = out + B_ * TQ * DIM;    // [B, Tq, Tv]  = 131072 floats

    float* WQ = (float*)d_ws;             // [1024,1024] fp32 = 4 MB
    float* WK = WQ + 1024 * 1024;         // [1024,1024] fp32 = 4 MB

    hipLaunchKernelGGL(k_proj,    dim3(16, 16, 2), dim3(256), 0, stream,
                       query, value, W1, W2, WQ, WK);
    hipLaunchKernelGGL(k_scores,  dim3(8, 8, 8),   dim3(256), 0, stream,
                       WQ, WK, scale, mask, attn);
    hipLaunchKernelGGL(k_softmax, dim3(256),       dim3(256), 0, stream, attn);
    hipLaunchKernelGGL(k_context, dim3(4, 8, 8),   dim3(256), 0, stream,
                       attn, value, ctx);
}

// Round 2
// 145.751 us; speedup vs baseline: 1.0392x; 1.0392x over previous
//
#include <hip/hip_runtime.h>

#define B_  8
#define TQ  128
#define TV  128
#define DIM 512
#define UU  1024
#define NSPLIT 4   // u-splits for k_scores
#define NP  (B_ * TQ * TV)   // 131072 elements per partial plane

// ---------------------------------------------------------------------------
// Kernel 1: dual fp32 tiled GEMM.  z=0: WQ = Q@W1 ; z=1: WK = V@W2
// M=1024 (B*T), N=1024 (U), K=512 (D). 32x64 tile / block, 2x4 per thread.
// grid 16x32x2 = 1024 blocks -> 4 blocks/CU (50% occupancy).
// ---------------------------------------------------------------------------
__global__ __launch_bounds__(256) void k_proj(
    const float* __restrict__ Q, const float* __restrict__ Vv,
    const float* __restrict__ W1, const float* __restrict__ W2,
    float* __restrict__ WQ, float* __restrict__ WK)
{
    const int N = UU, K = DIM;
    const float* A = blockIdx.z ? Vv : Q;
    const float* W = blockIdx.z ? W2 : W1;
    float*       C = blockIdx.z ? WK : WQ;

    __shared__ float As[32][34];   // [k][m], pitch 34: 8B-aligned float2 reads,
                                   // scatter-write bank = (8kq+2c+m)%32 -> 2-way (free)
    __shared__ float Bs[32][68];   // [k][n] padded

    const int tid  = threadIdx.x;
    const int tx   = tid & 15;     // n quad -> cols tx*4..+3
    const int ty   = tid >> 4;     // 0..15  -> rows ty*2, ty*2+1
    const int row0 = blockIdx.y * 32;
    const int col0 = blockIdx.x * 64;

    const int a_m  = tid >> 3;     // 0..31
    const int a_kq = tid & 7;      // float4 index along k
    const int b_n4 = (tid & 15) * 4;
    const int b_k  = tid >> 4;     // 0..15 (two halves)

    float acc[2][4] = {};

    for (int kt = 0; kt < K; kt += 32) {
        float4 av = *(const float4*)&A[(row0 + a_m) * K + kt + a_kq * 4];
        As[a_kq * 4 + 0][a_m] = av.x;
        As[a_kq * 4 + 1][a_m] = av.y;
        As[a_kq * 4 + 2][a_m] = av.z;
        As[a_kq * 4 + 3][a_m] = av.w;
        #pragma unroll
        for (int h = 0; h < 2; ++h) {
            int k = b_k + h * 16;
            *(float4*)&Bs[k][b_n4] = *(const float4*)&W[(kt + k) * N + col0 + b_n4];
        }
        __syncthreads();
        #pragma unroll
        for (int k = 0; k < 32; ++k) {
            float2 a  = *(const float2*)&As[k][ty * 2];
            float4 bv = *(const float4*)&Bs[k][tx * 4];
            acc[0][0] = fmaf(a.x, bv.x, acc[0][0]);
            acc[0][1] = fmaf(a.x, bv.y, acc[0][1]);
            acc[0][2] = fmaf(a.x, bv.z, acc[0][2]);
            acc[0][3] = fmaf(a.x, bv.w, acc[0][3]);
            acc[1][0] = fmaf(a.y, bv.x, acc[1][0]);
            acc[1][1] = fmaf(a.y, bv.y, acc[1][1]);
            acc[1][2] = fmaf(a.y, bv.z, acc[1][2]);
            acc[1][3] = fmaf(a.y, bv.w, acc[1][3]);
        }
        __syncthreads();
    }
    #pragma unroll
    for (int i = 0; i < 2; ++i) {
        float4 o = {acc[i][0], acc[i][1], acc[i][2], acc[i][3]};
        *(float4*)&C[(row0 + ty * 2 + i) * N + col0 + tx * 4] = o;
    }
}

// ---------------------------------------------------------------------------
// Kernel 2: partial scores. part[us][b][t][s] = sum_{u in range} s_u/(e^{2x_u}+1)
// pairwise-combined (one rcp per 2 u).  Actual score = const - 2*partials;
// the const (row-uniform) cancels in softmax, the -2 is applied there.
// qs/ks staged pre-scaled by 2*log2(e) so exp2 arg is a single add.
// grid (8,8,8*NSPLIT) = 2048 blocks -> 8 blocks/CU (100% occupancy cap).
// ---------------------------------------------------------------------------
__global__ __launch_bounds__(256) void k_scores(
    const float* __restrict__ WQ, const float* __restrict__ WK,
    const float* __restrict__ scale, float* __restrict__ part)
{
    __shared__ float qs[16][132];
    __shared__ float ks[16][132];
    __shared__ float ss[128];

    const int tid = threadIdx.x;
    const int tx  = tid & 15;   // s within tile
    const int ty  = tid >> 4;   // t within tile
    const int b   = blockIdx.z & 7;
    const int us  = blockIdx.z >> 3;    // 0..3
    const int t0  = blockIdx.y * 16;
    const int s0  = blockIdx.x * 16;
    const int u0  = us * (UU / NSPLIT); // 256-wide u range

    const int lr = tid >> 4;
    const int lc = (tid & 15) * 8;
    const float C2 = 2.885390081777927f;  // 2*log2(e)

    float acc = 0.f;
    for (int uc = u0; uc < u0 + UU / NSPLIT; uc += 128) {
        {
            const float* srq = &WQ[(b * TQ + t0 + lr) * UU + uc + lc];
            float4 q0 = *(const float4*)srq;
            float4 q1 = *(const float4*)(srq + 4);
            float4 a0 = {q0.x * C2, q0.y * C2, q0.z * C2, q0.w * C2};
            float4 a1 = {q1.x * C2, q1.y * C2, q1.z * C2, q1.w * C2};
            *(float4*)&qs[lr][lc]     = a0;
            *(float4*)&qs[lr][lc + 4] = a1;
            const float* srk = &WK[(b * TV + s0 + lr) * UU + uc + lc];
            float4 k0 = *(const float4*)srk;
            float4 k1 = *(const float4*)(srk + 4);
            float4 c0 = {k0.x * C2, k0.y * C2, k0.z * C2, k0.w * C2};
            float4 c1 = {k1.x * C2, k1.y * C2, k1.z * C2, k1.w * C2};
            *(float4*)&ks[lr][lc]     = c0;
            *(float4*)&ks[lr][lc + 4] = c1;
        }
        if (tid < 32)
            *(float4*)&ss[tid * 4] = *(const float4*)&scale[uc + tid * 4];
        __syncthreads();
        #pragma unroll 4
        for (int u4 = 0; u4 < 32; ++u4) {
            float4 q = *(const float4*)&qs[ty][u4 * 4];
            float4 k = *(const float4*)&ks[tx][u4 * 4];
            float4 s = *(const float4*)&ss[u4 * 4];
            // pair (x,y)
            float e1 = __builtin_amdgcn_exp2f(q.x + k.x);
            float e2 = __builtin_amdgcn_exp2f(q.y + k.y);
            float a1 = e1 + 1.f, a2 = e2 + 1.f;
            float n1 = fmaf(s.y, a1, s.x * a2);
            acc = fmaf(n1, __builtin_amdgcn_rcpf(a1 * a2), acc);
            // pair (z,w)
            float e3 = __builtin_amdgcn_exp2f(q.z + k.z);
            float e4 = __builtin_amdgcn_exp2f(q.w + k.w);
            float a3 = e3 + 1.f, a4 = e4 + 1.f;
            float n2 = fmaf(s.w, a3, s.z * a4);
            acc = fmaf(n2, __builtin_amdgcn_rcpf(a3 * a4), acc);
        }
        __syncthreads();
    }
    part[us * NP + ((b * TQ + t0 + ty) * TV) + s0 + tx] = acc;
}

// ---------------------------------------------------------------------------
// Kernel 3: combine partials -> logits = -2*sum(part), mask, softmax, -> attn.
// One wave per (b,t) row of 128. Grid 256 blocks x 4 waves.
// ---------------------------------------------------------------------------
__global__ __launch_bounds__(256) void k_softmax(
    const float* __restrict__ part, const int* __restrict__ mask,
    float* __restrict__ attn)
{
    const int tid  = threadIdx.x;
    const int wave = tid >> 6;
    const int lane = tid & 63;
    const int row  = blockIdx.x * 4 + wave;   // b*TQ + t
    const int b    = row >> 7;
    const int base = row * TV;

    float p0 = 0.f, p1 = 0.f;
    #pragma unroll
    for (int i = 0; i < NSPLIT; ++i) {
        p0 += part[i * NP + base + lane];
        p1 += part[i * NP + base + lane + 64];
    }
    float x0 = -2.f * p0, x1 = -2.f * p1;
    if (!mask[b * TV + lane])      x0 = -1e9f;
    if (!mask[b * TV + lane + 64]) x1 = -1e9f;

    float m = fmaxf(x0, x1);
    #pragma unroll
    for (int o = 32; o > 0; o >>= 1) m = fmaxf(m, __shfl_xor(m, o, 64));
    const float L2E = 1.4426950408889634f;
    float e0 = __builtin_amdgcn_exp2f((x0 - m) * L2E);
    float e1 = __builtin_amdgcn_exp2f((x1 - m) * L2E);
    float s = e0 + e1;
    #pragma unroll
    for (int o = 32; o > 0; o >>= 1) s += __shfl_xor(s, o, 64);
    float r = __builtin_amdgcn_rcpf(s);
    attn[base + lane]      = e0 * r;
    attn[base + lane + 64] = e1 * r;
}

// ---------------------------------------------------------------------------
// Kernel 4: context[b,t,d] = sum_s attn[b,t,s] * value[b,s,d]
// ---------------------------------------------------------------------------
__global__ __launch_bounds__(256) void k_context(
    const float* __restrict__ attn, const float* __restrict__ Vv,
    float* __restrict__ ctx)
{
    __shared__ float at[128][20];

    const int tid = threadIdx.x;
    const int b   = blockIdx.z;
    const int tt  = blockIdx.y;     // t tile of 16
    const int dc  = blockIdx.x;     // d chunk of 128
    {
        int tl = tid & 15;
        int s0 = (tid >> 4) * 8;
        const float* src = &attn[(b * TQ + tt * 16 + tl) * TV + s0];
        float4 a0 = *(const float4*)src;
        float4 a1 = *(const float4*)(src + 4);
        at[s0 + 0][tl] = a0.x; at[s0 + 1][tl] = a0.y;
        at[s0 + 2][tl] = a0.z; at[s0 + 3][tl] = a0.w;
        at[s0 + 4][tl] = a1.x; at[s0 + 5][tl] = a1.y;
        at[s0 + 6][tl] = a1.z; at[s0 + 7][tl] = a1.w;
    }
    __syncthreads();

    const int d  = (tid & 127) + dc * 128;
    const int tg = tid >> 7;
    float acc[8] = {};
    const float* vp = &Vv[b * TV * DIM + d];
    for (int s = 0; s < TV; ++s) {
        float v = vp[s * DIM];
        float4 a0 = *(const float4*)&at[s][tg * 8];
        float4 a1 = *(const float4*)&at[s][tg * 8 + 4];
        acc[0] = fmaf(a0.x, v, acc[0]);
        acc[1] = fmaf(a0.y, v, acc[1]);
        acc[2] = fmaf(a0.z, v, acc[2]);
        acc[3] = fmaf(a0.w, v, acc[3]);
        acc[4] = fmaf(a1.x, v, acc[4]);
        acc[5] = fmaf(a1.y, v, acc[5]);
        acc[6] = fmaf(a1.z, v, acc[6]);
        acc[7] = fmaf(a1.w, v, acc[7]);
    }
    #pragma unroll
    for (int j = 0; j < 8; ++j) {
        int t = tt * 16 + tg * 8 + j;
        ctx[(b * TQ + t) * DIM + d] = acc[j];
    }
}

// ---------------------------------------------------------------------------
extern "C" void kernel_launch(void* const* d_in, const int* in_sizes, int n_in,
                              void* d_out, int out_size, void* d_ws, size_t ws_size,
                              hipStream_t stream)
{
    const float* query = (const float*)d_in[0];
    const float* value = (const float*)d_in[1];
    const int*   mask  = (const int*)d_in[2];
    const float* W1    = (const float*)d_in[3];
    const float* W2    = (const float*)d_in[4];
    const float* scale = (const float*)d_in[5];

    float* out  = (float*)d_out;
    float* ctx  = out;                    // [B, Tq, D]
    float* attn = out + B_ * TQ * DIM;    // [B, Tq, Tv]

    float* WQ   = (float*)d_ws;           // 4 MB
    float* WK   = WQ + 1024 * 1024;       // 4 MB
    float* part = WK + 1024 * 1024;       // NSPLIT * 512 KB = 2 MB

    hipLaunchKernelGGL(k_proj,    dim3(16, 32, 2),          dim3(256), 0, stream,
                       query, value, W1, W2, WQ, WK);
    hipLaunchKernelGGL(k_scores,  dim3(8, 8, 8 * NSPLIT),   dim3(256), 0, stream,
                       WQ, WK, scale, part);
    hipLaunchKernelGGL(k_softmax, dim3(256),                dim3(256), 0, stream,
                       part, mask, attn);
    hipLaunchKernelGGL(k_context, dim3(4, 8, 8),            dim3(256), 0, stream,
                       attn, value, ctx);
}

// Round 3
// 130.208 us; speedup vs baseline: 1.1633x; 1.1194x over previous
//
#include <hip/hip_runtime.h>

#define B_  8
#define TQ  128
#define TV  128
#define DIM 512
#define UU  1024
#define NSPLIT 8             // u-splits for k_scores (u-chunk = 128)
#define NP  (B_ * TQ * TV)   // elements per partial plane
#define C2  2.885390081777927f   // 2*log2(e)

// ---------------------------------------------------------------------------
// Kernel 1: dual fp32 tiled GEMM + fused exp2 epilogue.
//   z=0: Eq = exp2(C2 * (Q@W1)) ; z=1: Ek = exp2(C2 * (V@W2))
// M=1024, N=1024 (U), K=512 (D). 64x64 tile / block, 4x4 per thread.
// ---------------------------------------------------------------------------
__global__ __launch_bounds__(256) void k_proj(
    const float* __restrict__ Q, const float* __restrict__ Vv,
    const float* __restrict__ W1, const float* __restrict__ W2,
    float* __restrict__ Eq, float* __restrict__ Ek)
{
    const int N = UU, K = DIM;
    const float* A = blockIdx.z ? Vv : Q;
    const float* W = blockIdx.z ? W2 : W1;
    float*       C = blockIdx.z ? Ek : Eq;

    __shared__ float As[32][68];   // [k][m], transposed on store
    __shared__ float Bs[32][68];   // [k][n]

    const int tid  = threadIdx.x;
    const int tx   = tid & 15;     // n quad
    const int ty   = tid >> 4;     // m quad
    const int row0 = blockIdx.y * 64;
    const int col0 = blockIdx.x * 64;

    const int a_m  = tid >> 2;     // 0..63
    const int a_kq = tid & 3;      // 8-k group
    const int b_n4 = (tid & 15) * 4;
    const int b_k  = tid >> 4;     // 0..15 (two halves)

    float acc[4][4] = {};

    for (int kt = 0; kt < K; kt += 32) {
        const float* ap = &A[(row0 + a_m) * K + kt + a_kq * 8];
        float4 a0 = *(const float4*)ap;
        float4 a1 = *(const float4*)(ap + 4);
        As[a_kq * 8 + 0][a_m] = a0.x;
        As[a_kq * 8 + 1][a_m] = a0.y;
        As[a_kq * 8 + 2][a_m] = a0.z;
        As[a_kq * 8 + 3][a_m] = a0.w;
        As[a_kq * 8 + 4][a_m] = a1.x;
        As[a_kq * 8 + 5][a_m] = a1.y;
        As[a_kq * 8 + 6][a_m] = a1.z;
        As[a_kq * 8 + 7][a_m] = a1.w;
        #pragma unroll
        for (int h = 0; h < 2; ++h) {
            int k = b_k + h * 16;
            *(float4*)&Bs[k][b_n4] = *(const float4*)&W[(kt + k) * N + col0 + b_n4];
        }
        __syncthreads();
        #pragma unroll
        for (int k = 0; k < 32; ++k) {
            float4 a = *(const float4*)&As[k][ty * 4];
            float4 b = *(const float4*)&Bs[k][tx * 4];
            float af[4] = {a.x, a.y, a.z, a.w};
            float bf[4] = {b.x, b.y, b.z, b.w};
            #pragma unroll
            for (int i = 0; i < 4; ++i)
                #pragma unroll
                for (int j = 0; j < 4; ++j)
                    acc[i][j] = fmaf(af[i], bf[j], acc[i][j]);
        }
        __syncthreads();
    }
    #pragma unroll
    for (int i = 0; i < 4; ++i) {
        float4 o;
        o.x = __builtin_amdgcn_exp2f(C2 * acc[i][0]);
        o.y = __builtin_amdgcn_exp2f(C2 * acc[i][1]);
        o.z = __builtin_amdgcn_exp2f(C2 * acc[i][2]);
        o.w = __builtin_amdgcn_exp2f(C2 * acc[i][3]);
        *(float4*)&C[(row0 + ty * 4 + i) * N + col0 + tx * 4] = o;
    }
}

// ---------------------------------------------------------------------------
// Kernel 2: partial scores via E-products (NO exp in the 134M-element loop).
//   tanh(x_u) = 1 - 2/(Eq*Ek + 1);  part = sum_u s_u/(Eq*Ek+1)
//   logits = const - 2*part (const row-uniform -> cancels in softmax).
// 32x32 (t,s) tile/block, 2x2 per thread, u-chunk of 128 per block.
// grid (4,4,8*NSPLIT) = 1024 blocks -> 4 blocks/CU.
// ---------------------------------------------------------------------------
__global__ __launch_bounds__(256) void k_scores(
    const float* __restrict__ Eq, const float* __restrict__ Ek,
    const float* __restrict__ scale, float* __restrict__ part)
{
    __shared__ float qs[32][132];
    __shared__ float ks[32][132];
    __shared__ float ss[128];

    const int tid = threadIdx.x;
    const int tx  = tid & 15;
    const int ty  = tid >> 4;          // 0..15
    const int b   = blockIdx.z & 7;
    const int us  = blockIdx.z >> 3;   // 0..7
    const int t0  = blockIdx.y * 32;
    const int s0  = blockIdx.x * 32;
    const int u0  = us * (UU / NSPLIT);

    // staging: 32 lanes cover one 128-float row; 4 rows per pass
    {
        const int c = (tid & 31) * 4;
        const int r0 = tid >> 5;       // 0..7
        #pragma unroll
        for (int i = 0; i < 4; ++i) {
            int r = r0 + i * 8;
            *(float4*)&qs[r][c] = *(const float4*)&Eq[(b * TQ + t0 + r) * UU + u0 + c];
            *(float4*)&ks[r][c] = *(const float4*)&Ek[(b * TV + s0 + r) * UU + u0 + c];
        }
        if (tid < 32)
            *(float4*)&ss[tid * 4] = *(const float4*)&scale[u0 + tid * 4];
    }
    __syncthreads();

    float a00 = 0.f, a01 = 0.f, a10 = 0.f, a11 = 0.f;

    #pragma unroll 4
    for (int u4 = 0; u4 < 32; ++u4) {
        float4 q0 = *(const float4*)&qs[ty][u4 * 4];
        float4 q1 = *(const float4*)&qs[ty + 16][u4 * 4];
        float4 k0 = *(const float4*)&ks[tx][u4 * 4];
        float4 k1 = *(const float4*)&ks[tx + 16][u4 * 4];
        float4 sv = *(const float4*)&ss[u4 * 4];

        #define PAIR(ACC, QV, KV)                                           \
        {                                                                   \
            float p1 = QV.x * KV.x, p2 = QV.y * KV.y;                       \
            float b1 = p1 + 1.f,   b2 = p2 + 1.f;                           \
            float n1 = fmaf(sv.y, b1, sv.x * b2);                           \
            ACC = fmaf(n1, __builtin_amdgcn_rcpf(b1 * b2), ACC);            \
            float p3 = QV.z * KV.z, p4 = QV.w * KV.w;                       \
            float b3 = p3 + 1.f,   b4 = p4 + 1.f;                           \
            float n2 = fmaf(sv.w, b3, sv.z * b4);                           \
            ACC = fmaf(n2, __builtin_amdgcn_rcpf(b3 * b4), ACC);            \
        }
        PAIR(a00, q0, k0)
        PAIR(a01, q0, k1)
        PAIR(a10, q1, k0)
        PAIR(a11, q1, k1)
        #undef PAIR
    }

    const int t = t0 + ty, s = s0 + tx;
    float* p = &part[us * NP + (b * TQ + t) * TV + s];
    p[0]            = a00;
    p[16]           = a01;
    p[16 * TV]      = a10;
    p[16 * TV + 16] = a11;
}

// ---------------------------------------------------------------------------
// Kernel 3: combine partials -> logits = -2*sum(part), mask, softmax -> attn.
// ---------------------------------------------------------------------------
__global__ __launch_bounds__(256) void k_softmax(
    const float* __restrict__ part, const int* __restrict__ mask,
    float* __restrict__ attn)
{
    const int tid  = threadIdx.x;
    const int wave = tid >> 6;
    const int lane = tid & 63;
    const int row  = blockIdx.x * 4 + wave;   // b*TQ + t
    const int b    = row >> 7;
    const int base = row * TV;

    float p0 = 0.f, p1 = 0.f;
    #pragma unroll
    for (int i = 0; i < NSPLIT; ++i) {
        p0 += part[i * NP + base + lane];
        p1 += part[i * NP + base + lane + 64];
    }
    float x0 = -2.f * p0, x1 = -2.f * p1;
    if (!mask[b * TV + lane])      x0 = -1e9f;
    if (!mask[b * TV + lane + 64]) x1 = -1e9f;

    float m = fmaxf(x0, x1);
    #pragma unroll
    for (int o = 32; o > 0; o >>= 1) m = fmaxf(m, __shfl_xor(m, o, 64));
    const float L2E = 1.4426950408889634f;
    float e0 = __builtin_amdgcn_exp2f((x0 - m) * L2E);
    float e1 = __builtin_amdgcn_exp2f((x1 - m) * L2E);
    float s = e0 + e1;
    #pragma unroll
    for (int o = 32; o > 0; o >>= 1) s += __shfl_xor(s, o, 64);
    float r = __builtin_amdgcn_rcpf(s);
    attn[base + lane]      = e0 * r;
    attn[base + lane + 64] = e1 * r;
}

// ---------------------------------------------------------------------------
// Kernel 4: context[b,t,d] = sum_s attn[b,t,s] * value[b,s,d]
// ---------------------------------------------------------------------------
__global__ __launch_bounds__(256) void k_context(
    const float* __restrict__ attn, const float* __restrict__ Vv,
    float* __restrict__ ctx)
{
    __shared__ float at[128][20];

    const int tid = threadIdx.x;
    const int b   = blockIdx.z;
    const int tt  = blockIdx.y;
    const int dc  = blockIdx.x;
    {
        int tl = tid & 15;
        int s0 = (tid >> 4) * 8;
        const float* src = &attn[(b * TQ + tt * 16 + tl) * TV + s0];
        float4 a0 = *(const float4*)src;
        float4 a1 = *(const float4*)(src + 4);
        at[s0 + 0][tl] = a0.x; at[s0 + 1][tl] = a0.y;
        at[s0 + 2][tl] = a0.z; at[s0 + 3][tl] = a0.w;
        at[s0 + 4][tl] = a1.x; at[s0 + 5][tl] = a1.y;
        at[s0 + 6][tl] = a1.z; at[s0 + 7][tl] = a1.w;
    }
    __syncthreads();

    const int d  = (tid & 127) + dc * 128;
    const int tg = tid >> 7;
    float acc[8] = {};
    const float* vp = &Vv[b * TV * DIM + d];
    for (int s = 0; s < TV; ++s) {
        float v = vp[s * DIM];
        float4 a0 = *(const float4*)&at[s][tg * 8];
        float4 a1 = *(const float4*)&at[s][tg * 8 + 4];
        acc[0] = fmaf(a0.x, v, acc[0]);
        acc[1] = fmaf(a0.y, v, acc[1]);
        acc[2] = fmaf(a0.z, v, acc[2]);
        acc[3] = fmaf(a0.w, v, acc[3]);
        acc[4] = fmaf(a1.x, v, acc[4]);
        acc[5] = fmaf(a1.y, v, acc[5]);
        acc[6] = fmaf(a1.z, v, acc[6]);
        acc[7] = fmaf(a1.w, v, acc[7]);
    }
    #pragma unroll
    for (int j = 0; j < 8; ++j) {
        int t = tt * 16 + tg * 8 + j;
        ctx[(b * TQ + t) * DIM + d] = acc[j];
    }
}

// ---------------------------------------------------------------------------
extern "C" void kernel_launch(void* const* d_in, const int* in_sizes, int n_in,
                              void* d_out, int out_size, void* d_ws, size_t ws_size,
                              hipStream_t stream)
{
    const float* query = (const float*)d_in[0];
    const float* value = (const float*)d_in[1];
    const int*   mask  = (const int*)d_in[2];
    const float* W1    = (const float*)d_in[3];
    const float* W2    = (const float*)d_in[4];
    const float* scale = (const float*)d_in[5];

    float* out  = (float*)d_out;
    float* ctx  = out;                    // [B, Tq, D]
    float* attn = out + B_ * TQ * DIM;    // [B, Tq, Tv]

    float* Eq   = (float*)d_ws;           // 4 MB  [1024][1024]
    float* Ek   = Eq + 1024 * 1024;       // 4 MB
    float* part = Ek + 1024 * 1024;       // NSPLIT * 512 KB = 4 MB

    hipLaunchKernelGGL(k_proj,    dim3(16, 16, 2),        dim3(256), 0, stream,
                       query, value, W1, W2, Eq, Ek);
    hipLaunchKernelGGL(k_scores,  dim3(4, 4, 8 * NSPLIT), dim3(256), 0, stream,
                       Eq, Ek, scale, part);
    hipLaunchKernelGGL(k_softmax, dim3(256),              dim3(256), 0, stream,
                       part, mask, attn);
    hipLaunchKernelGGL(k_context, dim3(4, 8, 8),          dim3(256), 0, stream,
                       attn, value, ctx);
}

// Round 4
// 117.530 us; speedup vs baseline: 1.2888x; 1.1079x over previous
//
#include <hip/hip_runtime.h>

#define B_  8
#define TQ  128
#define TV  128
#define DIM 512
#define UU  1024
#define NSPLIT 8             // u-splits for k_scores (u-chunk = 128)
#define NP  (B_ * TQ * TV)   // elements per partial plane
#define C2  2.885390081777927f   // 2*log2(e)

typedef __attribute__((ext_vector_type(8))) short     short8;   // 8 bf16 (4 VGPRs)
typedef __attribute__((ext_vector_type(4))) float     f32x4;
typedef __attribute__((ext_vector_type(4))) unsigned short us4;

__device__ __forceinline__ unsigned short bf16_rtne(float x) {
    unsigned u = __float_as_uint(x);
    unsigned r = u + 0x7FFF + ((u >> 16) & 1);
    return (unsigned short)(r >> 16);
}
__device__ __forceinline__ float bf16_to_f(unsigned short h) {
    return __uint_as_float(((unsigned)h) << 16);
}

// ---------------------------------------------------------------------------
// Prep A: split Q,V (each [1024][512] fp32) into hi/lo bf16 planes [2][1024][512].
// ---------------------------------------------------------------------------
__global__ __launch_bounds__(256) void k_prep_a(
    const float* __restrict__ Q, const float* __restrict__ Vv,
    unsigned short* __restrict__ Ah, unsigned short* __restrict__ Al)
{
    int idx = blockIdx.x * 256 + threadIdx.x;   // float4 index, 2*131072 total
    int mat = idx >> 17;
    const float* src = mat ? Vv : Q;
    int off = (idx & 131071) * 4;
    float4 v = *(const float4*)&src[off];
    us4 h, l;
    h.x = bf16_rtne(v.x); l.x = bf16_rtne(v.x - bf16_to_f(h.x));
    h.y = bf16_rtne(v.y); l.y = bf16_rtne(v.y - bf16_to_f(h.y));
    h.z = bf16_rtne(v.z); l.z = bf16_rtne(v.z - bf16_to_f(h.z));
    h.w = bf16_rtne(v.w); l.w = bf16_rtne(v.w - bf16_to_f(h.w));
    *(us4*)&Ah[mat * 524288 + off] = h;
    *(us4*)&Al[mat * 524288 + off] = l;
}

// ---------------------------------------------------------------------------
// Prep W: transpose W1,W2 ([512 k][1024 n] fp32) -> WT[2][1024 n][512 k] hi/lo bf16.
// 32x32 tiles via LDS.
// ---------------------------------------------------------------------------
__global__ __launch_bounds__(256) void k_prep_w(
    const float* __restrict__ W1, const float* __restrict__ W2,
    unsigned short* __restrict__ Wh, unsigned short* __restrict__ Wl)
{
    __shared__ float ts[32][36];
    const int t   = threadIdx.x;
    const int mat = blockIdx.z;
    const int n0  = blockIdx.x * 32;
    const int k0  = blockIdx.y * 32;
    const float* W = mat ? W2 : W1;

    int kk = t >> 3, n4 = (t & 7) * 4;
    float4 w = *(const float4*)&W[(k0 + kk) * UU + n0 + n4];
    ts[n4 + 0][kk] = w.x; ts[n4 + 1][kk] = w.y;
    ts[n4 + 2][kk] = w.z; ts[n4 + 3][kk] = w.w;
    __syncthreads();

    int nn = t >> 3, k4 = (t & 7) * 4;
    float4 v = *(const float4*)&ts[nn][k4];
    us4 h, l;
    h.x = bf16_rtne(v.x); l.x = bf16_rtne(v.x - bf16_to_f(h.x));
    h.y = bf16_rtne(v.y); l.y = bf16_rtne(v.y - bf16_to_f(h.y));
    h.z = bf16_rtne(v.z); l.z = bf16_rtne(v.z - bf16_to_f(h.z));
    h.w = bf16_rtne(v.w); l.w = bf16_rtne(v.w - bf16_to_f(h.w));
    unsigned off = mat * 524288 + (n0 + nn) * 512 + k0 + k4;
    *(us4*)&Wh[off] = h;
    *(us4*)&Wl[off] = l;
}

// ---------------------------------------------------------------------------
// Kernel 1: dual GEMM via split-bf16 MFMA + fused exp2 epilogue.
//   C = Ah*Bh + Ah*Bl + Al*Bh  (fp32-class accuracy), then exp2(C2*C).
// 64x64 tile, 4 waves in 2x2 arrangement, BK=32, 16x16x32 MFMA.
// grid (16,16,2) = 512 blocks.
// ---------------------------------------------------------------------------
#define PK 40   // LDS pitch in shorts: 80 B -> 16B-aligned b128, <=4-way banks
__global__ __launch_bounds__(256) void k_proj(
    const unsigned short* __restrict__ Ah, const unsigned short* __restrict__ Al,
    const unsigned short* __restrict__ Bh, const unsigned short* __restrict__ Bl,
    float* __restrict__ Eq, float* __restrict__ Ek)
{
    __shared__ short sAh[64 * PK], sAl[64 * PK], sBh[64 * PK], sBl[64 * PK];

    const int tid  = threadIdx.x;
    const int wave = tid >> 6;
    const int lane = tid & 63;
    const int mat  = blockIdx.z;
    const int m0   = blockIdx.y * 64;
    const int n0   = blockIdx.x * 64;

    const unsigned mb = mat * 524288u;
    const int wm = (wave & 1) * 32;
    const int wn = (wave >> 1) * 32;

    // staging: thread t covers row sm (0..63), 16-B granule sg (0..3)
    const int sm = tid >> 2, sg = tid & 3;
    const unsigned short* gAh = Ah + mb + (m0 + sm) * 512 + sg * 8;
    const unsigned short* gAl = Al + mb + (m0 + sm) * 512 + sg * 8;
    const unsigned short* gBh = Bh + mb + (n0 + sm) * 512 + sg * 8;
    const unsigned short* gBl = Bl + mb + (n0 + sm) * 512 + sg * 8;
    const int sOff = sm * PK + sg * 8;

    // fragment offsets
    const int fr = lane & 15, fq = lane >> 4;
    const int aOff0 = (wm + fr) * PK + fq * 8;
    const int aOff1 = (wm + 16 + fr) * PK + fq * 8;
    const int bOff0 = (wn + fr) * PK + fq * 8;
    const int bOff1 = (wn + 16 + fr) * PK + fq * 8;

    f32x4 acc00 = {0.f, 0.f, 0.f, 0.f};
    f32x4 acc01 = {0.f, 0.f, 0.f, 0.f};
    f32x4 acc10 = {0.f, 0.f, 0.f, 0.f};
    f32x4 acc11 = {0.f, 0.f, 0.f, 0.f};

    for (int kc = 0; kc < 16; ++kc) {
        int4 vah = *(const int4*)(gAh + kc * 32);
        int4 val = *(const int4*)(gAl + kc * 32);
        int4 vbh = *(const int4*)(gBh + kc * 32);
        int4 vbl = *(const int4*)(gBl + kc * 32);
        *(int4*)&sAh[sOff] = vah;
        *(int4*)&sAl[sOff] = val;
        *(int4*)&sBh[sOff] = vbh;
        *(int4*)&sBl[sOff] = vbl;
        __syncthreads();

        short8 a0h = *(const short8*)&sAh[aOff0];
        short8 a0l = *(const short8*)&sAl[aOff0];
        short8 a1h = *(const short8*)&sAh[aOff1];
        short8 a1l = *(const short8*)&sAl[aOff1];
        short8 b0h = *(const short8*)&sBh[bOff0];
        short8 b0l = *(const short8*)&sBl[bOff0];
        short8 b1h = *(const short8*)&sBh[bOff1];
        short8 b1l = *(const short8*)&sBl[bOff1];

        acc00 = __builtin_amdgcn_mfma_f32_16x16x32_bf16(a0h, b0h, acc00, 0, 0, 0);
        acc00 = __builtin_amdgcn_mfma_f32_16x16x32_bf16(a0h, b0l, acc00, 0, 0, 0);
        acc00 = __builtin_amdgcn_mfma_f32_16x16x32_bf16(a0l, b0h, acc00, 0, 0, 0);

        acc01 = __builtin_amdgcn_mfma_f32_16x16x32_bf16(a0h, b1h, acc01, 0, 0, 0);
        acc01 = __builtin_amdgcn_mfma_f32_16x16x32_bf16(a0h, b1l, acc01, 0, 0, 0);
        acc01 = __builtin_amdgcn_mfma_f32_16x16x32_bf16(a0l, b1h, acc01, 0, 0, 0);

        acc10 = __builtin_amdgcn_mfma_f32_16x16x32_bf16(a1h, b0h, acc10, 0, 0, 0);
        acc10 = __builtin_amdgcn_mfma_f32_16x16x32_bf16(a1h, b0l, acc10, 0, 0, 0);
        acc10 = __builtin_amdgcn_mfma_f32_16x16x32_bf16(a1l, b0h, acc10, 0, 0, 0);

        acc11 = __builtin_amdgcn_mfma_f32_16x16x32_bf16(a1h, b1h, acc11, 0, 0, 0);
        acc11 = __builtin_amdgcn_mfma_f32_16x16x32_bf16(a1h, b1l, acc11, 0, 0, 0);
        acc11 = __builtin_amdgcn_mfma_f32_16x16x32_bf16(a1l, b1h, acc11, 0, 0, 0);
        __syncthreads();
    }

    float* C = mat ? Ek : Eq;
    #pragma unroll
    for (int r = 0; r < 4; ++r) {
        int row0 = m0 + wm + fq * 4 + r;
        int row1 = row0 + 16;
        int col0 = n0 + wn + fr;
        C[row0 * UU + col0]      = __builtin_amdgcn_exp2f(C2 * acc00[r]);
        C[row0 * UU + col0 + 16] = __builtin_amdgcn_exp2f(C2 * acc01[r]);
        C[row1 * UU + col0]      = __builtin_amdgcn_exp2f(C2 * acc10[r]);
        C[row1 * UU + col0 + 16] = __builtin_amdgcn_exp2f(C2 * acc11[r]);
    }
}
#undef PK

// ---------------------------------------------------------------------------
// Kernel 2: partial scores via E-products (no exp in the 134M-element loop).
//   tanh(x_u) = 1 - 2/(Eq*Ek + 1);  part = sum_u s_u/(Eq*Ek+1)
// ---------------------------------------------------------------------------
__global__ __launch_bounds__(256) void k_scores(
    const float* __restrict__ Eq, const float* __restrict__ Ek,
    const float* __restrict__ scale, float* __restrict__ part)
{
    __shared__ float qs[32][132];
    __shared__ float ks[32][132];
    __shared__ float ss[128];

    const int tid = threadIdx.x;
    const int tx  = tid & 15;
    const int ty  = tid >> 4;
    const int b   = blockIdx.z & 7;
    const int us  = blockIdx.z >> 3;
    const int t0  = blockIdx.y * 32;
    const int s0  = blockIdx.x * 32;
    const int u0  = us * (UU / NSPLIT);

    {
        const int c  = (tid & 31) * 4;
        const int r0 = tid >> 5;
        #pragma unroll
        for (int i = 0; i < 4; ++i) {
            int r = r0 + i * 8;
            *(float4*)&qs[r][c] = *(const float4*)&Eq[(b * TQ + t0 + r) * UU + u0 + c];
            *(float4*)&ks[r][c] = *(const float4*)&Ek[(b * TV + s0 + r) * UU + u0 + c];
        }
        if (tid < 32)
            *(float4*)&ss[tid * 4] = *(const float4*)&scale[u0 + tid * 4];
    }
    __syncthreads();

    float a00 = 0.f, a01 = 0.f, a10 = 0.f, a11 = 0.f;

    #pragma unroll 4
    for (int u4 = 0; u4 < 32; ++u4) {
        float4 q0 = *(const float4*)&qs[ty][u4 * 4];
        float4 q1 = *(const float4*)&qs[ty + 16][u4 * 4];
        float4 k0 = *(const float4*)&ks[tx][u4 * 4];
        float4 k1 = *(const float4*)&ks[tx + 16][u4 * 4];
        float4 sv = *(const float4*)&ss[u4 * 4];

        #define PAIR(ACC, QV, KV)                                           \
        {                                                                   \
            float p1 = QV.x * KV.x, p2 = QV.y * KV.y;                       \
            float b1 = p1 + 1.f,   b2 = p2 + 1.f;                           \
            float n1 = fmaf(sv.y, b1, sv.x * b2);                           \
            ACC = fmaf(n1, __builtin_amdgcn_rcpf(b1 * b2), ACC);            \
            float p3 = QV.z * KV.z, p4 = QV.w * KV.w;                       \
            float b3 = p3 + 1.f,   b4 = p4 + 1.f;                           \
            float n2 = fmaf(sv.w, b3, sv.z * b4);                           \
            ACC = fmaf(n2, __builtin_amdgcn_rcpf(b3 * b4), ACC);            \
        }
        PAIR(a00, q0, k0)
        PAIR(a01, q0, k1)
        PAIR(a10, q1, k0)
        PAIR(a11, q1, k1)
        #undef PAIR
    }

    const int t = t0 + ty, s = s0 + tx;
    float* p = &part[us * NP + (b * TQ + t) * TV + s];
    p[0]            = a00;
    p[16]           = a01;
    p[16 * TV]      = a10;
    p[16 * TV + 16] = a11;
}

// ---------------------------------------------------------------------------
// Kernel 3: combine partials -> logits = -2*sum(part), mask, softmax -> attn.
// ---------------------------------------------------------------------------
__global__ __launch_bounds__(256) void k_softmax(
    const float* __restrict__ part, const int* __restrict__ mask,
    float* __restrict__ attn)
{
    const int tid  = threadIdx.x;
    const int wave = tid >> 6;
    const int lane = tid & 63;
    const int row  = blockIdx.x * 4 + wave;
    const int b    = row >> 7;
    const int base = row * TV;

    float p0 = 0.f, p1 = 0.f;
    #pragma unroll
    for (int i = 0; i < NSPLIT; ++i) {
        p0 += part[i * NP + base + lane];
        p1 += part[i * NP + base + lane + 64];
    }
    float x0 = -2.f * p0, x1 = -2.f * p1;
    if (!mask[b * TV + lane])      x0 = -1e9f;
    if (!mask[b * TV + lane + 64]) x1 = -1e9f;

    float m = fmaxf(x0, x1);
    #pragma unroll
    for (int o = 32; o > 0; o >>= 1) m = fmaxf(m, __shfl_xor(m, o, 64));
    const float L2E = 1.4426950408889634f;
    float e0 = __builtin_amdgcn_exp2f((x0 - m) * L2E);
    float e1 = __builtin_amdgcn_exp2f((x1 - m) * L2E);
    float s = e0 + e1;
    #pragma unroll
    for (int o = 32; o > 0; o >>= 1) s += __shfl_xor(s, o, 64);
    float r = __builtin_amdgcn_rcpf(s);
    attn[base + lane]      = e0 * r;
    attn[base + lane + 64] = e1 * r;
}

// ---------------------------------------------------------------------------
// Kernel 4: context[b,t,d] = sum_s attn[b,t,s] * value[b,s,d]
// ---------------------------------------------------------------------------
__global__ __launch_bounds__(256) void k_context(
    const float* __restrict__ attn, const float* __restrict__ Vv,
    float* __restrict__ ctx)
{
    __shared__ float at[128][20];

    const int tid = threadIdx.x;
    const int b   = blockIdx.z;
    const int tt  = blockIdx.y;
    const int dc  = blockIdx.x;
    {
        int tl = tid & 15;
        int s0 = (tid >> 4) * 8;
        const float* src = &attn[(b * TQ + tt * 16 + tl) * TV + s0];
        float4 a0 = *(const float4*)src;
        float4 a1 = *(const float4*)(src + 4);
        at[s0 + 0][tl] = a0.x; at[s0 + 1][tl] = a0.y;
        at[s0 + 2][tl] = a0.z; at[s0 + 3][tl] = a0.w;
        at[s0 + 4][tl] = a1.x; at[s0 + 5][tl] = a1.y;
        at[s0 + 6][tl] = a1.z; at[s0 + 7][tl] = a1.w;
    }
    __syncthreads();

    const int d  = (tid & 127) + dc * 128;
    const int tg = tid >> 7;
    float acc[8] = {};
    const float* vp = &Vv[b * TV * DIM + d];
    for (int s = 0; s < TV; ++s) {
        float v = vp[s * DIM];
        float4 a0 = *(const float4*)&at[s][tg * 8];
        float4 a1 = *(const float4*)&at[s][tg * 8 + 4];
        acc[0] = fmaf(a0.x, v, acc[0]);
        acc[1] = fmaf(a0.y, v, acc[1]);
        acc[2] = fmaf(a0.z, v, acc[2]);
        acc[3] = fmaf(a0.w, v, acc[3]);
        acc[4] = fmaf(a1.x, v, acc[4]);
        acc[5] = fmaf(a1.y, v, acc[5]);
        acc[6] = fmaf(a1.z, v, acc[6]);
        acc[7] = fmaf(a1.w, v, acc[7]);
    }
    #pragma unroll
    for (int j = 0; j < 8; ++j) {
        int t = tt * 16 + tg * 8 + j;
        ctx[(b * TQ + t) * DIM + d] = acc[j];
    }
}

// ---------------------------------------------------------------------------
extern "C" void kernel_launch(void* const* d_in, const int* in_sizes, int n_in,
                              void* d_out, int out_size, void* d_ws, size_t ws_size,
                              hipStream_t stream)
{
    const float* query = (const float*)d_in[0];
    const float* value = (const float*)d_in[1];
    const int*   mask  = (const int*)d_in[2];
    const float* W1    = (const float*)d_in[3];
    const float* W2    = (const float*)d_in[4];
    const float* scale = (const float*)d_in[5];

    float* out  = (float*)d_out;
    float* ctx  = out;                    // [B, Tq, D]
    float* attn = out + B_ * TQ * DIM;    // [B, Tq, Tv]

    float* Eq   = (float*)d_ws;           // 4 MB
    float* Ek   = Eq + 1024 * 1024;       // 4 MB
    float* part = Ek + 1024 * 1024;       // 4 MB
    unsigned short* Ah = (unsigned short*)(part + NSPLIT * NP);  // 2 MB
    unsigned short* Al = Ah + 2 * 1024 * 512;                    // 2 MB
    unsigned short* Wh = Al + 2 * 1024 * 512;                    // 2 MB
    unsigned short* Wl = Wh + 2 * 1024 * 512;                    // 2 MB

    hipLaunchKernelGGL(k_prep_a, dim3(1024),       dim3(256), 0, stream,
                       query, value, Ah, Al);
    hipLaunchKernelGGL(k_prep_w, dim3(32, 16, 2),  dim3(256), 0, stream,
                       W1, W2, Wh, Wl);
    hipLaunchKernelGGL(k_proj,   dim3(16, 16, 2),  dim3(256), 0, stream,
                       Ah, Al, Wh, Wl, Eq, Ek);
    hipLaunchKernelGGL(k_scores, dim3(4, 4, 8 * NSPLIT), dim3(256), 0, stream,
                       Eq, Ek, scale, part);
    hipLaunchKernelGGL(k_softmax, dim3(256),       dim3(256), 0, stream,
                       part, mask, attn);
    hipLaunchKernelGGL(k_context, dim3(4, 8, 8),   dim3(256), 0, stream,
                       attn, value, ctx);
}

// Round 5
// 112.900 us; speedup vs baseline: 1.3416x; 1.0410x over previous
//
#include <hip/hip_runtime.h>

#define B_  8
#define TQ  128
#define TV  128
#define DIM 512
#define UU  1024
#define NSPLIT 8             // u-splits for k_scores (u-chunk = 128)
#define NP  (B_ * TQ * TV)   // elements per partial plane
#define C2  2.885390081777927f   // 2*log2(e)

typedef __attribute__((ext_vector_type(8))) short     short8;   // 8 bf16 (4 VGPRs)
typedef __attribute__((ext_vector_type(4))) float     f32x4;
typedef __attribute__((ext_vector_type(4))) unsigned short us4;

__device__ __forceinline__ unsigned short bf16_rtne(float x) {
    unsigned u = __float_as_uint(x);
    unsigned r = u + 0x7FFF + ((u >> 16) & 1);
    return (unsigned short)(r >> 16);
}
__device__ __forceinline__ float bf16_to_f(unsigned short h) {
    return __uint_as_float(((unsigned)h) << 16);
}

// ---------------------------------------------------------------------------
// Prep (merged): blocks 0..1023: split Q,V -> Ah/Al bf16 hi/lo.
//               blocks 1024..2047: transpose+split W1,W2 -> Wh/Wl [n][k].
// ---------------------------------------------------------------------------
__global__ __launch_bounds__(256) void k_prep(
    const float* __restrict__ Q, const float* __restrict__ Vv,
    const float* __restrict__ W1, const float* __restrict__ W2,
    unsigned short* __restrict__ Ah, unsigned short* __restrict__ Al,
    unsigned short* __restrict__ Wh, unsigned short* __restrict__ Wl)
{
    __shared__ float ts[32][36];
    const int bx = blockIdx.x;
    const int t  = threadIdx.x;

    if (bx < 1024) {
        int idx = bx * 256 + t;            // float4 index, 2*131072 total
        int mat = idx >> 17;
        const float* src = mat ? Vv : Q;
        int off = (idx & 131071) * 4;
        float4 v = *(const float4*)&src[off];
        us4 h, l;
        h.x = bf16_rtne(v.x); l.x = bf16_rtne(v.x - bf16_to_f(h.x));
        h.y = bf16_rtne(v.y); l.y = bf16_rtne(v.y - bf16_to_f(h.y));
        h.z = bf16_rtne(v.z); l.z = bf16_rtne(v.z - bf16_to_f(h.z));
        h.w = bf16_rtne(v.w); l.w = bf16_rtne(v.w - bf16_to_f(h.w));
        *(us4*)&Ah[mat * 524288 + off] = h;
        *(us4*)&Al[mat * 524288 + off] = l;
    } else {
        int b2   = bx - 1024;
        int mat  = b2 >> 9;
        int tile = b2 & 511;               // 32 n-tiles x 16 k-tiles
        int n0 = (tile & 31) * 32;
        int k0 = (tile >> 5) * 32;
        const float* W = mat ? W2 : W1;

        int kk = t >> 3, n4 = (t & 7) * 4;
        float4 w = *(const float4*)&W[(k0 + kk) * UU + n0 + n4];
        ts[n4 + 0][kk] = w.x; ts[n4 + 1][kk] = w.y;
        ts[n4 + 2][kk] = w.z; ts[n4 + 3][kk] = w.w;
        __syncthreads();

        int nn = t >> 3, k4 = (t & 7) * 4;
        float4 v = *(const float4*)&ts[nn][k4];
        us4 h, l;
        h.x = bf16_rtne(v.x); l.x = bf16_rtne(v.x - bf16_to_f(h.x));
        h.y = bf16_rtne(v.y); l.y = bf16_rtne(v.y - bf16_to_f(h.y));
        h.z = bf16_rtne(v.z); l.z = bf16_rtne(v.z - bf16_to_f(h.z));
        h.w = bf16_rtne(v.w); l.w = bf16_rtne(v.w - bf16_to_f(h.w));
        unsigned off = mat * 524288 + (n0 + nn) * 512 + k0 + k4;
        *(us4*)&Wh[off] = h;
        *(us4*)&Wl[off] = l;
    }
}

// ---------------------------------------------------------------------------
// Kernel 1: dual GEMM via split-bf16 MFMA + fused exp2 epilogue.
//   C = Ah*Bh + Ah*Bl + Al*Bh, then exp2(C2*C).
// 64x64 tile, 4 waves 2x2, BK=64, unroll-1 K-loop with register prefetch.
// grid (16,16,2) = 512 blocks -> 2 blocks/CU.
// ---------------------------------------------------------------------------
#define PKP 72   // shorts pitch: 144 B. read/write bank classes uniform -> b128 floor
__global__ __launch_bounds__(256) void k_proj(
    const unsigned short* __restrict__ Ah, const unsigned short* __restrict__ Al,
    const unsigned short* __restrict__ Bh, const unsigned short* __restrict__ Bl,
    float* __restrict__ Eq, float* __restrict__ Ek)
{
    __shared__ short sAh[64 * PKP], sAl[64 * PKP], sBh[64 * PKP], sBl[64 * PKP];

    const int tid  = threadIdx.x;
    const int wave = tid >> 6;
    const int lane = tid & 63;
    const int mat  = blockIdx.z;
    const int m0   = blockIdx.y * 64;
    const int n0   = blockIdx.x * 64;

    const unsigned mb = mat * 524288u;
    const int wm = (wave & 1) * 32;
    const int wn = (wave >> 1) * 32;

    // staging: thread covers row sm (0..63), granules sg and sg+4 of 8 (BK=64)
    const int sm = tid >> 2, sg = tid & 3;
    const unsigned short* gAh = Ah + mb + (m0 + sm) * 512;
    const unsigned short* gAl = Al + mb + (m0 + sm) * 512;
    const unsigned short* gBh = Bh + mb + (n0 + sm) * 512;
    const unsigned short* gBl = Bl + mb + (n0 + sm) * 512;
    const int so0 = sm * PKP + sg * 8;
    const int so1 = sm * PKP + 32 + sg * 8;

    // fragment offsets
    const int fr = lane & 15, fq = lane >> 4;
    const int aOff0 = (wm + fr) * PKP + fq * 8;
    const int aOff1 = (wm + 16 + fr) * PKP + fq * 8;
    const int bOff0 = (wn + fr) * PKP + fq * 8;
    const int bOff1 = (wn + 16 + fr) * PKP + fq * 8;

    f32x4 acc00 = {0.f, 0.f, 0.f, 0.f};
    f32x4 acc01 = {0.f, 0.f, 0.f, 0.f};
    f32x4 acc10 = {0.f, 0.f, 0.f, 0.f};
    f32x4 acc11 = {0.f, 0.f, 0.f, 0.f};

    int4 rAh0, rAh1, rAl0, rAl1, rBh0, rBh1, rBl0, rBl1;
    #define LOADALL(K)                                                       \
        rAh0 = *(const int4*)(gAh + (K) + sg * 8);                           \
        rAh1 = *(const int4*)(gAh + (K) + 32 + sg * 8);                      \
        rAl0 = *(const int4*)(gAl + (K) + sg * 8);                           \
        rAl1 = *(const int4*)(gAl + (K) + 32 + sg * 8);                      \
        rBh0 = *(const int4*)(gBh + (K) + sg * 8);                           \
        rBh1 = *(const int4*)(gBh + (K) + 32 + sg * 8);                      \
        rBl0 = *(const int4*)(gBl + (K) + sg * 8);                           \
        rBl1 = *(const int4*)(gBl + (K) + 32 + sg * 8);

    LOADALL(0)

    #pragma unroll 1
    for (int kc = 0; kc < 8; ++kc) {
        *(int4*)&sAh[so0] = rAh0;  *(int4*)&sAh[so1] = rAh1;
        *(int4*)&sAl[so0] = rAl0;  *(int4*)&sAl[so1] = rAl1;
        *(int4*)&sBh[so0] = rBh0;  *(int4*)&sBh[so1] = rBh1;
        *(int4*)&sBl[so0] = rBl0;  *(int4*)&sBl[so1] = rBl1;
        __syncthreads();

        if (kc < 7) { LOADALL((kc + 1) * 64) }   // overlap next-load with MFMA

        #pragma unroll
        for (int ks = 0; ks < 2; ++ks) {
            const int o = ks * 32;
            short8 a0h = *(const short8*)&sAh[aOff0 + o];
            short8 a0l = *(const short8*)&sAl[aOff0 + o];
            short8 a1h = *(const short8*)&sAh[aOff1 + o];
            short8 a1l = *(const short8*)&sAl[aOff1 + o];
            short8 b0h = *(const short8*)&sBh[bOff0 + o];
            short8 b0l = *(const short8*)&sBl[bOff0 + o];
            short8 b1h = *(const short8*)&sBh[bOff1 + o];
            short8 b1l = *(const short8*)&sBl[bOff1 + o];

            acc00 = __builtin_amdgcn_mfma_f32_16x16x32_bf16(a0h, b0h, acc00, 0, 0, 0);
            acc00 = __builtin_amdgcn_mfma_f32_16x16x32_bf16(a0h, b0l, acc00, 0, 0, 0);
            acc00 = __builtin_amdgcn_mfma_f32_16x16x32_bf16(a0l, b0h, acc00, 0, 0, 0);

            acc01 = __builtin_amdgcn_mfma_f32_16x16x32_bf16(a0h, b1h, acc01, 0, 0, 0);
            acc01 = __builtin_amdgcn_mfma_f32_16x16x32_bf16(a0h, b1l, acc01, 0, 0, 0);
            acc01 = __builtin_amdgcn_mfma_f32_16x16x32_bf16(a0l, b1h, acc01, 0, 0, 0);

            acc10 = __builtin_amdgcn_mfma_f32_16x16x32_bf16(a1h, b0h, acc10, 0, 0, 0);
            acc10 = __builtin_amdgcn_mfma_f32_16x16x32_bf16(a1h, b0l, acc10, 0, 0, 0);
            acc10 = __builtin_amdgcn_mfma_f32_16x16x32_bf16(a1l, b0h, acc10, 0, 0, 0);

            acc11 = __builtin_amdgcn_mfma_f32_16x16x32_bf16(a1h, b1h, acc11, 0, 0, 0);
            acc11 = __builtin_amdgcn_mfma_f32_16x16x32_bf16(a1h, b1l, acc11, 0, 0, 0);
            acc11 = __builtin_amdgcn_mfma_f32_16x16x32_bf16(a1l, b1h, acc11, 0, 0, 0);
        }
        __syncthreads();
    }
    #undef LOADALL

    float* C = mat ? Ek : Eq;
    #pragma unroll
    for (int r = 0; r < 4; ++r) {
        int row0 = m0 + wm + fq * 4 + r;
        int row1 = row0 + 16;
        int col0 = n0 + wn + fr;
        C[row0 * UU + col0]      = __builtin_amdgcn_exp2f(C2 * acc00[r]);
        C[row0 * UU + col0 + 16] = __builtin_amdgcn_exp2f(C2 * acc01[r]);
        C[row1 * UU + col0]      = __builtin_amdgcn_exp2f(C2 * acc10[r]);
        C[row1 * UU + col0 + 16] = __builtin_amdgcn_exp2f(C2 * acc11[r]);
    }
}
#undef PKP

// ---------------------------------------------------------------------------
// Kernel 2: partial scores via E-products (no exp in the 134M-element loop).
//   tanh(x_u) = 1 - 2/(Eq*Ek + 1);  part = sum_u s_u/(Eq*Ek+1)
// ---------------------------------------------------------------------------
__global__ __launch_bounds__(256) void k_scores(
    const float* __restrict__ Eq, const float* __restrict__ Ek,
    const float* __restrict__ scale, float* __restrict__ part)
{
    __shared__ float qs[32][132];
    __shared__ float ks[32][132];
    __shared__ float ss[128];

    const int tid = threadIdx.x;
    const int tx  = tid & 15;
    const int ty  = tid >> 4;
    const int b   = blockIdx.z & 7;
    const int us  = blockIdx.z >> 3;
    const int t0  = blockIdx.y * 32;
    const int s0  = blockIdx.x * 32;
    const int u0  = us * (UU / NSPLIT);

    {
        const int c  = (tid & 31) * 4;
        const int r0 = tid >> 5;
        #pragma unroll
        for (int i = 0; i < 4; ++i) {
            int r = r0 + i * 8;
            *(float4*)&qs[r][c] = *(const float4*)&Eq[(b * TQ + t0 + r) * UU + u0 + c];
            *(float4*)&ks[r][c] = *(const float4*)&Ek[(b * TV + s0 + r) * UU + u0 + c];
        }
        if (tid < 32)
            *(float4*)&ss[tid * 4] = *(const float4*)&scale[u0 + tid * 4];
    }
    __syncthreads();

    float a00 = 0.f, a01 = 0.f, a10 = 0.f, a11 = 0.f;

    #pragma unroll 4
    for (int u4 = 0; u4 < 32; ++u4) {
        float4 q0 = *(const float4*)&qs[ty][u4 * 4];
        float4 q1 = *(const float4*)&qs[ty + 16][u4 * 4];
        float4 k0 = *(const float4*)&ks[tx][u4 * 4];
        float4 k1 = *(const float4*)&ks[tx + 16][u4 * 4];
        float4 sv = *(const float4*)&ss[u4 * 4];

        #define PAIR(ACC, QV, KV)                                           \
        {                                                                   \
            float p1 = QV.x * KV.x, p2 = QV.y * KV.y;                       \
            float b1 = p1 + 1.f,   b2 = p2 + 1.f;                           \
            float n1 = fmaf(sv.y, b1, sv.x * b2);                           \
            ACC = fmaf(n1, __builtin_amdgcn_rcpf(b1 * b2), ACC);            \
            float p3 = QV.z * KV.z, p4 = QV.w * KV.w;                       \
            float b3 = p3 + 1.f,   b4 = p4 + 1.f;                           \
            float n2 = fmaf(sv.w, b3, sv.z * b4);                           \
            ACC = fmaf(n2, __builtin_amdgcn_rcpf(b3 * b4), ACC);            \
        }
        PAIR(a00, q0, k0)
        PAIR(a01, q0, k1)
        PAIR(a10, q1, k0)
        PAIR(a11, q1, k1)
        #undef PAIR
    }

    const int t = t0 + ty, s = s0 + tx;
    float* p = &part[us * NP + (b * TQ + t) * TV + s];
    p[0]            = a00;
    p[16]           = a01;
    p[16 * TV]      = a10;
    p[16 * TV + 16] = a11;
}

// ---------------------------------------------------------------------------
// Kernel 3 (fused): softmax from partials + context.
// Block (dc, tt, b): 16 t-rows, d-chunk of 128. Softmax recomputed per dc;
// attn written to d_out only by dc==0 blocks.
// ---------------------------------------------------------------------------
__global__ __launch_bounds__(256) void k_ctx(
    const float* __restrict__ part, const int* __restrict__ mask,
    const float* __restrict__ Vv,
    float* __restrict__ attn, float* __restrict__ ctx)
{
    __shared__ float at[128][20];

    const int tid = threadIdx.x;
    const int dc  = blockIdx.x;     // d chunk of 128
    const int tt  = blockIdx.y;     // t tile of 16
    const int b   = blockIdx.z;
    const int t0  = tt * 16;
    const int rg  = tid >> 4;       // local row 0..15
    const int ln  = tid & 15;
    const int base = (b * TQ + t0 + rg) * TV;

    // ---- softmax phase: each thread owns 8 s-positions of one row ----
    float x[8];
    #pragma unroll
    for (int j = 0; j < 8; ++j) {
        const int s = ln + 16 * j;
        float p = 0.f;
        #pragma unroll
        for (int i = 0; i < NSPLIT; ++i) p += part[i * NP + base + s];
        x[j] = mask[b * TV + s] ? -2.f * p : -1e9f;
    }
    float m = x[0];
    #pragma unroll
    for (int j = 1; j < 8; ++j) m = fmaxf(m, x[j]);
    #pragma unroll
    for (int o = 8; o > 0; o >>= 1) m = fmaxf(m, __shfl_xor(m, o, 64));
    const float L2E = 1.4426950408889634f;
    float e[8];
    float sum = 0.f;
    #pragma unroll
    for (int j = 0; j < 8; ++j) {
        e[j] = __builtin_amdgcn_exp2f((x[j] - m) * L2E);
        sum += e[j];
    }
    #pragma unroll
    for (int o = 8; o > 0; o >>= 1) sum += __shfl_xor(sum, o, 64);
    const float r = __builtin_amdgcn_rcpf(sum);
    #pragma unroll
    for (int j = 0; j < 8; ++j) {
        const float a = e[j] * r;
        at[ln + 16 * j][rg] = a;                    // transposed for phase 2
        if (dc == 0) attn[base + ln + 16 * j] = a;  // write output once
    }
    __syncthreads();

    // ---- context phase ----
    const int d  = (tid & 127) + dc * 128;
    const int tg = tid >> 7;
    float acc[8] = {};
    const float* vp = &Vv[b * TV * DIM + d];
    for (int s = 0; s < TV; ++s) {
        float v = vp[s * DIM];
        float4 a0 = *(const float4*)&at[s][tg * 8];
        float4 a1 = *(const float4*)&at[s][tg * 8 + 4];
        acc[0] = fmaf(a0.x, v, acc[0]);
        acc[1] = fmaf(a0.y, v, acc[1]);
        acc[2] = fmaf(a0.z, v, acc[2]);
        acc[3] = fmaf(a0.w, v, acc[3]);
        acc[4] = fmaf(a1.x, v, acc[4]);
        acc[5] = fmaf(a1.y, v, acc[5]);
        acc[6] = fmaf(a1.z, v, acc[6]);
        acc[7] = fmaf(a1.w, v, acc[7]);
    }
    #pragma unroll
    for (int j = 0; j < 8; ++j) {
        int t = t0 + tg * 8 + j;
        ctx[(b * TQ + t) * DIM + d] = acc[j];
    }
}

// ---------------------------------------------------------------------------
extern "C" void kernel_launch(void* const* d_in, const int* in_sizes, int n_in,
                              void* d_out, int out_size, void* d_ws, size_t ws_size,
                              hipStream_t stream)
{
    const float* query = (const float*)d_in[0];
    const float* value = (const float*)d_in[1];
    const int*   mask  = (const int*)d_in[2];
    const float* W1    = (const float*)d_in[3];
    const float* W2    = (const float*)d_in[4];
    const float* scale = (const float*)d_in[5];

    float* out  = (float*)d_out;
    float* ctx  = out;                    // [B, Tq, D]
    float* attn = out + B_ * TQ * DIM;    // [B, Tq, Tv]

    float* Eq   = (float*)d_ws;           // 4 MB
    float* Ek   = Eq + 1024 * 1024;       // 4 MB
    float* part = Ek + 1024 * 1024;       // 4 MB
    unsigned short* Ah = (unsigned short*)(part + NSPLIT * NP);  // 2 MB
    unsigned short* Al = Ah + 2 * 1024 * 512;                    // 2 MB
    unsigned short* Wh = Al + 2 * 1024 * 512;                    // 2 MB
    unsigned short* Wl = Wh + 2 * 1024 * 512;                    // 2 MB

    hipLaunchKernelGGL(k_prep,   dim3(2048),            dim3(256), 0, stream,
                       query, value, W1, W2, Ah, Al, Wh, Wl);
    hipLaunchKernelGGL(k_proj,   dim3(16, 16, 2),       dim3(256), 0, stream,
                       Ah, Al, Wh, Wl, Eq, Ek);
    hipLaunchKernelGGL(k_scores, dim3(4, 4, 8 * NSPLIT), dim3(256), 0, stream,
                       Eq, Ek, scale, part);
    hipLaunchKernelGGL(k_ctx,    dim3(4, 8, 8),         dim3(256), 0, stream,
                       part, mask, value, attn, ctx);
}